// Round 1
// baseline (305.985 us; speedup 1.0000x reference)
//
#include <hip/hip_runtime.h>
#include <hip/hip_fp16.h>

// ---------------- problem constants ----------------
// B=32768, D_IN=256, H1=256, D_OUT=64, E=32, T=16
#define NTHR 512            // 8 waves
#define BM   128            // rows per block
#define NBLK 256            // 32768/128
#define NEXP 32

using f16x8 = __attribute__((ext_vector_type(8))) _Float16;
using f32x4 = __attribute__((ext_vector_type(4))) float;
using u32x4 = __attribute__((ext_vector_type(4))) unsigned int;

// workspace byte offsets
static constexpr size_t W1IMG_OFF = 0;            // 32*8*16384  = 4,194,304
static constexpr size_t W2IMG_OFF = 4194304;      // 32*32768    = 1,048,576
static constexpr size_t VIMG_OFF  = 5242880;      // 32*8192     =   262,144
static constexpr size_t KT_OFF    = 5505024;      // 16*32*64*4  =   131,072
// total 5,636,096 bytes of d_ws used

__device__ __forceinline__ unsigned short f2h(float x){
  _Float16 h = (_Float16)x;
  return __builtin_bit_cast(unsigned short, h);
}

union H8 { unsigned short s[8]; u32x4 v; f16x8 h; };

// ---------------------------------------------------------------------------
// prep 1: W1 [E][256][256] f32 -> fp16 image, per (e,kc) chunk of K=32:
//   chunk layout [n=256][k=32] halves, 16B-slot swizzle: slot b (=klocal/8)
//   stored at (b ^ ((n>>1)&3)).  16 KB per chunk, linear-copyable to LDS.
// ---------------------------------------------------------------------------
__global__ __launch_bounds__(256) void prep_w1(const float* __restrict__ W1,
                                               unsigned short* __restrict__ img){
  const int e = blockIdx.x >> 3, kc = blockIdx.x & 7;
  __shared__ unsigned short lw[32*256];
  const int t = threadIdx.x;
  {
    const int k  = t >> 3;              // 0..31 (k within chunk)
    const int n0 = (t & 7) * 32;        // col start
    const float* src = W1 + ((size_t)(e*256 + kc*32 + k))*256 + n0;
    #pragma unroll
    for (int i = 0; i < 4; i++){
      H8 h8;
      #pragma unroll
      for (int j = 0; j < 8; j += 4){
        float4 v = *reinterpret_cast<const float4*>(src + i*8 + j);
        h8.s[j+0]=f2h(v.x); h8.s[j+1]=f2h(v.y); h8.s[j+2]=f2h(v.z); h8.s[j+3]=f2h(v.w);
      }
      const int cb = (n0 >> 3) + i;     // col-block 0..31, XOR to avoid LDS write conflicts
      *reinterpret_cast<u32x4*>(&lw[k*256 + ((cb ^ (k & 7))<<3)]) = h8.v;
    }
  }
  __syncthreads();
  {
    const int n = t;                    // 0..255 output row (= H1 col)
    unsigned short* dst = img + (size_t)(e*8 + kc)*8192;
    #pragma unroll
    for (int b = 0; b < 4; b++){
      H8 h8;
      #pragma unroll
      for (int j = 0; j < 8; j++){
        const int kk = b*8 + j;
        h8.s[j] = lw[kk*256 + (((n>>3) ^ (kk & 7))<<3) + (n & 7)];
      }
      *reinterpret_cast<u32x4*>(dst + n*32 + ((b ^ ((n>>1)&3))<<3)) = h8.v;
    }
  }
}

// ---------------------------------------------------------------------------
// prep 2: W2 [E][256][64] -> image [n=64][k=256], slot s (=k/8) at (s^(n&15));
//         V  [E][64][64]  -> image [n=64][k=64],  slot s at (s^(n&7)).
// ---------------------------------------------------------------------------
__global__ __launch_bounds__(256) void prep_w2v(const float* __restrict__ W2,
                                                const float* __restrict__ V,
                                                unsigned short* __restrict__ w2img,
                                                unsigned short* __restrict__ vimg){
  const int t = threadIdx.x;
  if (blockIdx.x < 32){
    const int e = blockIdx.x;
    __shared__ unsigned short lw[256*64];
    {
      const int k = t;                           // 0..255
      const float* src = W2 + (size_t)(e*256 + k)*64;
      #pragma unroll
      for (int i = 0; i < 8; i++){
        H8 h8;
        #pragma unroll
        for (int j = 0; j < 8; j += 4){
          float4 v = *reinterpret_cast<const float4*>(src + i*8 + j);
          h8.s[j+0]=f2h(v.x); h8.s[j+1]=f2h(v.y); h8.s[j+2]=f2h(v.z); h8.s[j+3]=f2h(v.w);
        }
        *reinterpret_cast<u32x4*>(&lw[k*64 + ((i ^ (k & 7))<<3)]) = h8.v;
      }
    }
    __syncthreads();
    {
      unsigned short* dst = w2img + (size_t)e*16384;
      const int n = t >> 2, q = t & 3;
      #pragma unroll
      for (int u = 0; u < 8; u++){
        const int s = q*8 + u;
        H8 h8;
        #pragma unroll
        for (int j = 0; j < 8; j++){
          const int kk = s*8 + j;
          h8.s[j] = lw[kk*64 + (((n>>3) ^ (kk & 7))<<3) + (n & 7)];
        }
        *reinterpret_cast<u32x4*>(dst + n*256 + ((s ^ (n & 15))<<3)) = h8.v;
      }
    }
  } else {
    const int e = blockIdx.x - 32;
    __shared__ unsigned short lv[64*64];
    {
      const int k = t >> 2, c0 = (t & 3)*16;
      const float* src = V + (size_t)(e*64 + k)*64 + c0;
      #pragma unroll
      for (int i = 0; i < 2; i++){
        H8 h8;
        #pragma unroll
        for (int j = 0; j < 8; j += 4){
          float4 v = *reinterpret_cast<const float4*>(src + i*8 + j);
          h8.s[j+0]=f2h(v.x); h8.s[j+1]=f2h(v.y); h8.s[j+2]=f2h(v.z); h8.s[j+3]=f2h(v.w);
        }
        const int cb = (c0>>3) + i;
        *reinterpret_cast<u32x4*>(&lv[k*64 + ((cb ^ (k & 7))<<3)]) = h8.v;
      }
    }
    __syncthreads();
    {
      unsigned short* dst = vimg + (size_t)e*4096;
      #pragma unroll
      for (int pass = 0; pass < 2; pass++){
        const int id = t + pass*256;       // 0..511
        const int n = id >> 3, s = id & 7;
        H8 h8;
        #pragma unroll
        for (int j = 0; j < 8; j++){
          const int kk = s*8 + j;
          h8.s[j] = lv[kk*64 + (((n>>3) ^ (kk & 7))<<3) + (n & 7)];
        }
        *reinterpret_cast<u32x4*>(dst + n*64 + ((s ^ (n & 7))<<3)) = h8.v;
      }
    }
  }
}

// ---------------------------------------------------------------------------
// prep 3: kt[t][e][i] = sum_j K[e][i][j] * q[t][j]  (fp32), plus reg-loss scalar.
// ---------------------------------------------------------------------------
__global__ __launch_bounds__(256) void prep_kt(const float* __restrict__ Km,
                                               const float* __restrict__ Q,
                                               float* __restrict__ kt,
                                               float* __restrict__ out){
  const int e = blockIdx.x;     // 32 blocks
  const int t = threadIdx.x;
  #pragma unroll
  for (int pass = 0; pass < 4; pass++){
    const int id = t + pass*256;        // 0..1023
    const int tt = id >> 6, i = id & 63;
    const float4* Kr = reinterpret_cast<const float4*>(Km + (size_t)(e*64 + i)*64);
    const float4* qr = reinterpret_cast<const float4*>(Q + tt*64);
    float s = 0.f;
    #pragma unroll
    for (int j = 0; j < 16; j++){
      float4 a = Kr[j], b = qr[j];
      s += a.x*b.x + a.y*b.y + a.z*b.z + a.w*b.w;
    }
    kt[((size_t)tt*32 + e)*64 + i] = s;
  }
  // reg_loss = -(MU/E) * (B*1 + B*E*1e-6) ; softmax rows sum to 1.
  if (blockIdx.x == 0 && t == 0) out[(size_t)32768*64] = -10.24032768f;
}

// ---------------------------------------------------------------------------
// main fused kernel: per block = 128 rows, loop over 32 experts:
//   h = relu(X@W1_e + b1) -> eo = h@W2_e + b2 -> score = eo . kt[task][e]
//   -> pv = eo@V_e -> flash-style online softmax accumulation.
// LDS (160 KB): Xb fp16 [128][256] swz | h fp16 [128][256] swz |
//               wreg 32KB: W1 chunk dbuf / W2 full / (eo | V | kt)
// ---------------------------------------------------------------------------
__global__ __launch_bounds__(NTHR, 2)
void moe_main(const float* __restrict__ X, const int* __restrict__ task,
              const float* __restrict__ b1, const float* __restrict__ b2,
              const unsigned short* __restrict__ w1img,
              const unsigned short* __restrict__ w2img,
              const unsigned short* __restrict__ vimg,
              const float* __restrict__ ktg,
              float* __restrict__ out)
{
  __shared__ unsigned short smem[81920];      // 160 KB exactly
  unsigned short* Xb   = smem;                // [128][256] halves, slot^(row&15)
  unsigned short* hbuf = smem + 32768;        // [128][256] halves, slot^(row&15)
  unsigned short* wreg = smem + 65536;        // 16384 halves = 32 KB

  const int tid  = threadIdx.x;
  const int lane = tid & 63;
  const int wid  = tid >> 6;                  // 0..7
  const int g    = lane >> 4;                 // 0..3  (k-group / row-group)
  const int c    = lane & 15;                 // 0..15 (A-row / B-col / C-col)
  const int wm   = wid >> 2, wn = wid & 3;    // GEMM1 wave grid 2x4
  const int row0 = blockIdx.x * BM;

  // prefetch W1 e=0 chunk0 (consumed at e-loop top)
  u32x4 pfA, pfB;
  {
    const u32x4* g0 = reinterpret_cast<const u32x4*>(w1img) + tid;
    pfA = g0[0]; pfB = g0[512];
  }

  // ---- stage X tile (fp32 -> fp16, swizzled) ----
  #pragma unroll
  for (int pass = 0; pass < 8; pass++){
    const int id = tid + pass*NTHR;           // 0..4095
    const int r = id >> 5, s = id & 31;
    const float4* src = reinterpret_cast<const float4*>(X + (size_t)(row0 + r)*256 + s*8);
    float4 v0 = src[0], v1 = src[1];
    H8 h8;
    h8.s[0]=f2h(v0.x); h8.s[1]=f2h(v0.y); h8.s[2]=f2h(v0.z); h8.s[3]=f2h(v0.w);
    h8.s[4]=f2h(v1.x); h8.s[5]=f2h(v1.y); h8.s[6]=f2h(v1.z); h8.s[7]=f2h(v1.w);
    *reinterpret_cast<u32x4*>(&Xb[r*256 + ((s ^ (r & 15))<<3)]) = h8.v;
  }

  int mytask[4];
  #pragma unroll
  for (int rg = 0; rg < 4; rg++)
    mytask[rg] = task[row0 + wid*16 + 4*g + rg];

  float m_run[4], d_run[4], oacc[4][4];       // oacc[fn][rg]
  #pragma unroll
  for (int rg = 0; rg < 4; rg++){
    m_run[rg] = -1e30f; d_run[rg] = 0.f;
    #pragma unroll
    for (int fn = 0; fn < 4; fn++) oacc[fn][rg] = 0.f;
  }

  __syncthreads();    // X visible

  for (int e = 0; e < NEXP; e++){
    // write chunk0 into buf0 (prev expert's eo reads finished at sync E)
    {
      u32x4* d = reinterpret_cast<u32x4*>(wreg) + tid;
      d[0] = pfA; d[512] = pfB;
    }
    { // prefetch chunk1
      const u32x4* gs = reinterpret_cast<const u32x4*>(w1img + ((size_t)e*8 + 1)*8192) + tid;
      pfA = gs[0]; pfB = gs[512];
    }
    __syncthreads();  // F: buf0 visible

    f32x4 acc1[4][4] = {};
    u32x4 pfW2[4];

    // ---- GEMM1: h = X @ W1_e, K chunked by 32, double-buffered ----
    #pragma unroll
    for (int kc = 0; kc < 8; kc++){
      if (kc < 7){                            // write next chunk (other buffer)
        u32x4* d = reinterpret_cast<u32x4*>(wreg + ((kc+1)&1)*8192) + tid;
        d[0] = pfA; d[512] = pfB;
      }
      if (kc < 6){                            // prefetch chunk kc+2
        const u32x4* gs = reinterpret_cast<const u32x4*>(w1img + ((size_t)e*8 + kc + 2)*8192) + tid;
        pfA = gs[0]; pfB = gs[512];
      } else if (kc == 6){                    // prefetch W2 (32 KB)
        const u32x4* gs = reinterpret_cast<const u32x4*>(w2img + (size_t)e*16384) + tid;
        pfW2[0]=gs[0]; pfW2[1]=gs[512]; pfW2[2]=gs[1024]; pfW2[3]=gs[1536];
      }
      const unsigned short* wb = wreg + (kc & 1)*8192;
      f16x8 af[4], bf[4];
      #pragma unroll
      for (int fm = 0; fm < 4; fm++){
        const int r = wm*64 + fm*16 + c;
        af[fm] = *reinterpret_cast<const f16x8*>(&Xb[r*256 + (((kc*4 + g) ^ c)<<3)]);
      }
      #pragma unroll
      for (int fn = 0; fn < 4; fn++){
        const int n = wn*64 + fn*16 + c;
        bf[fn] = *reinterpret_cast<const f16x8*>(&wb[n*32 + ((g ^ ((n>>1)&3))<<3)]);
      }
      #pragma unroll
      for (int fm = 0; fm < 4; fm++)
        #pragma unroll
        for (int fn = 0; fn < 4; fn++)
          acc1[fm][fn] = __builtin_amdgcn_mfma_f32_16x16x32_f16(af[fm], bf[fn], acc1[fm][fn], 0, 0, 0);
      __syncthreads();
    }

    // ---- h = relu(acc1 + b1) -> LDS fp16 ----
    const float* b1e = b1 + e*256;
    #pragma unroll
    for (int fn = 0; fn < 4; fn++){
      const int colb = wn*64 + fn*16 + c;
      const float bias = b1e[colb];
      const int sw = colb >> 3, lo = colb & 7;
      #pragma unroll
      for (int fm = 0; fm < 4; fm++){
        #pragma unroll
        for (int rg = 0; rg < 4; rg++){
          const int rrow = wm*64 + fm*16 + 4*g + rg;
          float v = acc1[fm][fn][rg] + bias;
          v = fmaxf(v, 0.f);
          hbuf[rrow*256 + (((sw) ^ (rrow & 15))<<3) + lo] = f2h(v);
        }
      }
    }
    // write W2 into full wreg (chunk reads finished at kc=7 sync)
    {
      u32x4* d = reinterpret_cast<u32x4*>(wreg) + tid;
      d[0]=pfW2[0]; d[512]=pfW2[1]; d[1024]=pfW2[2]; d[1536]=pfW2[3];
    }
    // prefetch V, kt slice, next-expert chunk0
    u32x4 pfV;  float2 pfKT;
    {
      const u32x4* gv = reinterpret_cast<const u32x4*>(vimg + (size_t)e*4096) + tid;
      pfV = gv[0];
      pfKT = *reinterpret_cast<const float2*>(ktg + ((size_t)(tid>>5)*32 + e)*64 + ((tid*2)&63));
    }
    if (e + 1 < NEXP){
      const u32x4* gs = reinterpret_cast<const u32x4*>(w1img + (size_t)(e+1)*8*8192) + tid;
      pfA = gs[0]; pfB = gs[512];
    }
    __syncthreads();  // B: h + W2 visible

    // ---- GEMM2: eo = h @ W2_e  (per wave: 16 rows x 64 cols) ----
    f32x4 acc2[4] = {};
    #pragma unroll
    for (int ks = 0; ks < 8; ks++){
      const int rr = wid*16 + c;
      const f16x8 ah = *reinterpret_cast<const f16x8*>(&hbuf[rr*256 + (((ks*4 + g) ^ c)<<3)]);
      #pragma unroll
      for (int fn = 0; fn < 4; fn++){
        const int n = fn*16 + c;
        const f16x8 bw = *reinterpret_cast<const f16x8*>(&wreg[n*256 + (((ks*4 + g) ^ c)<<3)]);
        acc2[fn] = __builtin_amdgcn_mfma_f32_16x16x32_f16(ah, bw, acc2[fn], 0, 0, 0);
      }
    }
    __syncthreads();  // C: W2/h reads done, wreg reusable

    // ---- eo = acc2 + b2 : keep fp32 in regs, write fp16 to LDS for PV ----
    float eo_reg[4][4];
    const float* b2e = b2 + e*64;
    #pragma unroll
    for (int fn = 0; fn < 4; fn++){
      const float bias = b2e[fn*16 + c];
      const int colb = fn*16 + c;
      const int sw = colb >> 3, lo = colb & 7;
      #pragma unroll
      for (int rg = 0; rg < 4; rg++){
        const float v = acc2[fn][rg] + bias;
        eo_reg[fn][rg] = v;
        wreg[(wid*16 + 4*g + rg)*64 + ((sw ^ ((4*g + rg) & 7))<<3) + lo] = f2h(v);
      }
    }
    { // V and kt slices into LDS
      u32x4* dv = reinterpret_cast<u32x4*>(wreg + 8192) + tid;
      dv[0] = pfV;
      float* dk = reinterpret_cast<float*>(wreg + 12288);
      reinterpret_cast<float2*>(dk)[tid] = pfKT;
    }
    __syncthreads();  // D: eo/V/kt visible

    // ---- scores: s[row] = eo . kt[task[row]][e][:]  (reduce over 16 lanes) ----
    float part[4] = {0.f, 0.f, 0.f, 0.f};
    const float* ktl = reinterpret_cast<const float*>(wreg + 12288);
    #pragma unroll
    for (int rg = 0; rg < 4; rg++){
      const float* krow = ktl + mytask[rg]*64;
      #pragma unroll
      for (int fn = 0; fn < 4; fn++)
        part[rg] += eo_reg[fn][rg] * krow[fn*16 + c];
    }
    #pragma unroll
    for (int off = 1; off < 16; off <<= 1){
      #pragma unroll
      for (int rg = 0; rg < 4; rg++)
        part[rg] += __shfl_xor(part[rg], off);
    }

    // ---- PV: pv = eo @ V_e ----
    f32x4 pv[4] = {};
    #pragma unroll
    for (int ks2 = 0; ks2 < 2; ks2++){
      const int rr = wid*16 + c;
      const int sA = ks2*4 + g;
      const f16x8 ae = *reinterpret_cast<const f16x8*>(&wreg[rr*64 + ((sA ^ (c & 7))<<3)]);
      #pragma unroll
      for (int fn = 0; fn < 4; fn++){
        const int n = fn*16 + c;
        const f16x8 bv = *reinterpret_cast<const f16x8*>(&wreg[8192 + n*64 + ((sA ^ (c & 7))<<3)]);
        pv[fn] = __builtin_amdgcn_mfma_f32_16x16x32_f16(ae, bv, pv[fn], 0, 0, 0);
      }
    }

    // ---- online softmax update ----
    #pragma unroll
    for (int rg = 0; rg < 4; rg++){
      const float s = part[rg];
      const float mnew = fmaxf(m_run[rg], s);
      const float al = __expf(m_run[rg] - mnew);
      const float p  = __expf(s - mnew);
      d_run[rg] = d_run[rg]*al + p;
      m_run[rg] = mnew;
      #pragma unroll
      for (int fn = 0; fn < 4; fn++)
        oacc[fn][rg] = oacc[fn][rg]*al + p*pv[fn][rg];
    }
    __syncthreads();  // E: eo/V/kt reads done before next expert overwrites
  }

  // ---- output ----
  #pragma unroll
  for (int rg = 0; rg < 4; rg++){
    const float inv = 1.f / d_run[rg];
    const size_t grow = (size_t)(row0 + wid*16 + 4*g + rg) * 64;
    #pragma unroll
    for (int fn = 0; fn < 4; fn++)
      out[grow + fn*16 + c] = oacc[fn][rg] * inv;
  }
}

// ---------------------------------------------------------------------------
extern "C" void kernel_launch(void* const* d_in, const int* in_sizes, int n_in,
                              void* d_out, int out_size, void* d_ws, size_t ws_size,
                              hipStream_t stream)
{
  (void)in_sizes; (void)n_in; (void)out_size; (void)ws_size;
  const float* X   = (const float*)d_in[0];
  const int*   tsk = (const int*)  d_in[1];
  const float* W1  = (const float*)d_in[2];
  const float* b1  = (const float*)d_in[3];
  const float* W2  = (const float*)d_in[4];
  const float* b2  = (const float*)d_in[5];
  const float* Q   = (const float*)d_in[6];
  const float* Km  = (const float*)d_in[7];
  const float* Vm  = (const float*)d_in[8];
  float* out = (float*)d_out;

  unsigned char* ws = (unsigned char*)d_ws;
  unsigned short* w1img = (unsigned short*)(ws + W1IMG_OFF);
  unsigned short* w2img = (unsigned short*)(ws + W2IMG_OFF);
  unsigned short* vimg  = (unsigned short*)(ws + VIMG_OFF);
  float*          ktg   = (float*)(ws + KT_OFF);

  prep_w1 <<<dim3(256), dim3(256), 0, stream>>>(W1, w1img);
  prep_w2v<<<dim3(64),  dim3(256), 0, stream>>>(W2, Vm, w2img, vimg);
  prep_kt <<<dim3(32),  dim3(256), 0, stream>>>(Km, Q, ktg, out);
  moe_main<<<dim3(NBLK), dim3(NTHR), 0, stream>>>(X, tsk, b1, b2, w1img, w2img, vimg, ktg, out);
}